// Round 5
// baseline (2033.764 us; speedup 1.0000x reference)
//
#include <hip/hip_runtime.h>

// DepthFlowProjection (DAIN, fillhole=0) forward — LDS-privatized scatter,
// ILP-restructured (round 5).
//
// flow:  [B,2,H,W] f32, depth: [B,1,H,W] f32  -> out: [B,2,H,W] f32
//
// R1/2: device f32 atomics ~25 G/s -> privatize into LDS tiles.
// R4: correct 2-kernel version, but latency-bound (VALU 6.7%, HBM 5.6%,
//     bank-conflicts 0): scalar loads + branchy divergent atomics = serial
//     chain per iteration. R5: float4 halo loads (one col-iter per row),
//     1-deep software pipeline, predicated (branch-free) LDS corner adds
//     via per-lane dummy slot.

constexpr int W  = 1920, H = 1080;
constexpr int HW = W * H;
constexpr int Sh = 40, Wt = 160, R = 24;
constexpr int TX = W / Wt, TY = H / Sh;     // 12, 27
constexpr int SW = Sh * Wt;                 // 6400 px per tile
constexpr float LEAK_THR = (float)(R - 1);  // 23.0f

__global__ __launch_bounds__(512, 4) void dfp_tile(
    const float* __restrict__ flow, const float* __restrict__ depth,
    float* __restrict__ leak,      // [B*HW] float4 cells, zeroed
    float* __restrict__ cnt_out,   // raw tile cnt, stride cnt_stride
    int cnt_stride,
    float* __restrict__ out, int B)
{
    // planes: cnt, sx, sy + 64 per-lane dummy slots for non-owned corners
    __shared__ __align__(16) float acc[3 * SW + 64];
    const int tid  = threadIdx.x;
    const int lane = tid & 63;
    const int wid  = tid >> 6;
    const int dummy = 3 * SW + lane;

    int blk = blockIdx.x;
    int b   = blk / (TX * TY);
    int t   = blk - b * (TX * TY);
    int ty  = t / TX;
    int tx  = t - ty * TX;
    const int Y0 = ty * Sh, X0 = tx * Wt;

    float4* accv = (float4*)acc;
    for (int i = tid; i < (3 * SW + 64) / 4; i += 512)
        accv[i] = make_float4(0.f, 0.f, 0.f, 0.f);
    __syncthreads();

    const float* fxp = flow + (size_t)b * 2 * HW;
    const float* fyp = fxp + HW;
    const float* dp  = depth + (size_t)b * HW;

    const int r0 = max(Y0 - R, 0), r1 = min(Y0 + Sh + R, H);
    const int c0 = max(X0 - R, 0), c1 = min(X0 + Wt + R, W);
    // region width <= 208 <= 256 = 64 lanes * 4 px -> single col pass.
    // All of c0, c1, c1-4 are float4-aligned (X0 multiple of 160, R=24).
    const int ce = c0 + (lane << 2);     // this lane's nominal first col
    const int cl = min(ce, c1 - 4);      // clamped, aligned load col

    auto proc = [&](int r, float fx, float fy, float dv, int j) {
        int col = cl + j;
        bool cv = (ce + j) < c1;         // false for duplicated clamped elems
        float x2 = (float)col + fx;
        float y2 = (float)r + fy;
        bool valid = (x2 >= 0.f) & (y2 >= 0.f) &
                     (x2 <= (float)(W - 1)) & (y2 <= (float)(H - 1)) & cv;
        float de  = valid ? dv : 0.f;    // invalid contributes exactly 0 (ref)
        float vxe = -fx * de;
        float vye = -fy * de;
        int ixL = min(max((int)floorf(x2), 0), W - 1);
        int iyT = min(max((int)floorf(y2), 0), H - 1);
        int ixR = min(ixL + 1, W - 1);
        int iyB = min(iyT + 1, H - 1);
        bool small = (fabsf(fx) <= LEAK_THR) & (fabsf(fy) <= LEAK_THR);

        // predicated corner adds: non-owned -> per-lane dummy slot
#define DOCORNER(iy, ix) do {                                              \
        bool own = small & ((iy) >= Y0) & ((iy) < Y0 + Sh) &               \
                           ((ix) >= X0) & ((ix) < X0 + Wt);                \
        int o = ((iy) - Y0) * Wt + ((ix) - X0);                            \
        atomicAdd(&acc[own ? o          : dummy], de);                     \
        atomicAdd(&acc[own ? o + SW     : dummy], vxe);                    \
        atomicAdd(&acc[own ? o + 2 * SW : dummy], vye);                    \
    } while (0)
        DOCORNER(iyT, ixL); DOCORNER(iyT, ixR);
        DOCORNER(iyB, ixL); DOCORNER(iyB, ixR);
#undef DOCORNER

        // rare big-flow pixel: handled once, by its source-owning tile
        if (valid && !small &&
            r >= Y0 && r < Y0 + Sh && col >= X0 && col < X0 + Wt) {
            size_t base = (size_t)b * HW * 4;
            float vx = -fx * dv, vy = -fy * dv;
#define GCORNER(iy, ix) do {                                               \
        size_t o = base + (size_t)((iy) * W + (ix)) * 4;                   \
        atomicAdd(leak + o + 0, dv);                                       \
        atomicAdd(leak + o + 1, vx);                                       \
        atomicAdd(leak + o + 2, vy);                                       \
    } while (0)
            GCORNER(iyT, ixL); GCORNER(iyT, ixR);
            GCORNER(iyB, ixL); GCORNER(iyB, ixR);
#undef GCORNER
        }
    };

    // 1-deep software-pipelined row loop (rows partitioned by wave, stride 8)
    int r = r0 + wid;
    float4 fxc, fyc, dc;
    if (r < r1) {
        fxc = *(const float4*)(fxp + (size_t)r * W + cl);
        fyc = *(const float4*)(fyp + (size_t)r * W + cl);
        dc  = *(const float4*)(dp  + (size_t)r * W + cl);
    }
    for (; r < r1; r += 8) {
        int rn = r + 8;
        float4 fxn, fyn, dn;
        if (rn < r1) {
            fxn = *(const float4*)(fxp + (size_t)rn * W + cl);
            fyn = *(const float4*)(fyp + (size_t)rn * W + cl);
            dn  = *(const float4*)(dp  + (size_t)rn * W + cl);
        }
        proc(r, fxc.x, fyc.x, dc.x, 0);
        proc(r, fxc.y, fyc.y, dc.y, 1);
        proc(r, fxc.z, fyc.z, dc.z, 2);
        proc(r, fxc.w, fyc.w, dc.w, 3);
        fxc = fxn; fyc = fyn; dc = dn;
    }
    __syncthreads();

    // flush RAW sums: each output pixel owned by exactly one block.
    float* outx = out + (size_t)b * 2 * HW;
    float* outy = outx + HW;
    for (int i = tid; i < SW; i += 512) {
        int ly = i / Wt;
        int lx = i - ly * Wt;
        int gp = (Y0 + ly) * W + (X0 + lx);
        outx[gp] = acc[i + SW];
        outy[gp] = acc[i + 2 * SW];
        cnt_out[(size_t)((size_t)b * HW + gp) * cnt_stride] = acc[i];
    }
}

// Kernel 2: combine tile sums + leak, normalize (stream-ordered -> race-free).
__global__ void dfp_finalize(const float4* __restrict__ leak,
                             const float* __restrict__ cnt_in,
                             int cnt_stride,
                             float* __restrict__ out, int B)
{
    const long total = (long)B * HW;
    long idx = (long)blockIdx.x * blockDim.x + threadIdx.x;
    if (idx >= total) return;
    int b = (int)(idx / HW);
    int p = (int)(idx - (long)b * HW);

    float4 lk = leak[idx];
    float cnt = cnt_in[(size_t)idx * cnt_stride] + lk.x;
    float den = (cnt > 0.f) ? cnt : 1.f;

    size_t o = (size_t)b * 2 * HW + p;
    out[o]      = (out[o]      + lk.y) / den;
    out[o + HW] = (out[o + HW] + lk.z) / den;
}

// ---------------- fallback (round-1) path if ws is too small ----------------

__global__ void dfp_scatter(const float* __restrict__ flow,
                            const float* __restrict__ depth,
                            float* __restrict__ out,
                            float* __restrict__ count, int B)
{
    const long total = (long)B * HW;
    long idx = (long)blockIdx.x * blockDim.x + threadIdx.x;
    if (idx >= total) return;
    int b = (int)(idx / HW);
    int p = (int)(idx - (long)b * HW);
    int y = p / W;
    int x = p - y * W;
    const float* f = flow + (size_t)b * 2 * HW;
    float fx = f[p], fy = f[HW + p], d = depth[idx];
    float x2 = (float)x + fx, y2 = (float)y + fy;
    if (!(x2 >= 0.f && y2 >= 0.f && x2 <= (float)(W - 1) && y2 <= (float)(H - 1)))
        return;
    int ixL = min(max((int)floorf(x2), 0), W - 1);
    int iyT = min(max((int)floorf(y2), 0), H - 1);
    int ixR = min(ixL + 1, W - 1), iyB = min(iyT + 1, H - 1);
    float vx = -fx * d, vy = -fy * d;
    float* cnt_b  = count + (size_t)b * HW;
    float* outx_b = out + (size_t)b * 2 * HW;
    float* outy_b = outx_b + HW;
    int o00 = iyT * W + ixL, o01 = iyT * W + ixR;
    int o10 = iyB * W + ixL, o11 = iyB * W + ixR;
    atomicAdd(&cnt_b[o00], d);   atomicAdd(&cnt_b[o01], d);
    atomicAdd(&cnt_b[o10], d);   atomicAdd(&cnt_b[o11], d);
    atomicAdd(&outx_b[o00], vx); atomicAdd(&outx_b[o01], vx);
    atomicAdd(&outx_b[o10], vx); atomicAdd(&outx_b[o11], vx);
    atomicAdd(&outy_b[o00], vy); atomicAdd(&outy_b[o01], vy);
    atomicAdd(&outy_b[o10], vy); atomicAdd(&outy_b[o11], vy);
}

__global__ void dfp_normalize(float* __restrict__ out,
                              const float* __restrict__ count, int B)
{
    const long total = (long)B * HW;
    long idx = (long)blockIdx.x * blockDim.x + threadIdx.x;
    if (idx >= total) return;
    int b = (int)(idx / HW);
    int p = (int)(idx - (long)b * HW);
    float c = count[idx];
    float den = (c > 0.f) ? c : 1.f;
    size_t o = (size_t)b * 2 * HW + p;
    out[o]      = out[o] / den;
    out[o + HW] = out[o + HW] / den;
}

extern "C" void kernel_launch(void* const* d_in, const int* in_sizes, int n_in,
                              void* d_out, int out_size, void* d_ws, size_t ws_size,
                              hipStream_t stream) {
    const float* flow  = (const float*)d_in[0];
    const float* depth = (const float*)d_in[1];
    float* out = (float*)d_out;

    const int B = in_sizes[1] / HW;
    const long total = (long)B * HW;

    const size_t cell_bytes  = (size_t)total * 4 * sizeof(float);
    const size_t plane_bytes = (size_t)total * sizeof(float);

    const int fin_threads = 256;
    const int fin_blocks  = (int)((total + fin_threads - 1) / fin_threads);

    if (ws_size >= cell_bytes + plane_bytes) {
        float* leak = (float*)d_ws;
        float* cnt  = leak + (size_t)total * 4;
        hipMemsetAsync(d_ws, 0, cell_bytes, stream);
        dfp_tile<<<B * TX * TY, 512, 0, stream>>>(flow, depth, leak, cnt, 1, out, B);
        dfp_finalize<<<fin_blocks, fin_threads, 0, stream>>>((const float4*)leak, cnt, 1, out, B);
    } else if (ws_size >= cell_bytes) {
        float* leak = (float*)d_ws;
        hipMemsetAsync(d_ws, 0, cell_bytes, stream);
        dfp_tile<<<B * TX * TY, 512, 0, stream>>>(flow, depth, leak, leak + 3, 4, out, B);
        dfp_finalize<<<fin_blocks, fin_threads, 0, stream>>>((const float4*)leak, leak + 3, 4, out, B);
    } else {
        const int threads = 256;
        const int blocks = (int)((total + threads - 1) / threads);
        float* cnt = (float*)d_ws;
        hipMemsetAsync(d_out, 0, (size_t)total * 2 * sizeof(float), stream);
        hipMemsetAsync(d_ws, 0, plane_bytes, stream);
        dfp_scatter<<<blocks, threads, 0, stream>>>(flow, depth, out, cnt, B);
        dfp_normalize<<<blocks, threads, 0, stream>>>(out, cnt, B);
    }
}

// Round 6
// 605.156 us; speedup vs baseline: 3.3607x; 3.3607x over previous
//
#include <hip/hip_runtime.h>

// DepthFlowProjection (DAIN, fillhole=0) forward — LDS-privatized scatter.
// R6: R4's branchy corner adds (execz-skip is fast; R5's predication+dummy
// slots was a 3.3x regression) + small tile (20x160, 38.4KB LDS -> 4
// blocks/CU = 32 waves/CU) + float2 pipelined loads + XCD swizzle.

constexpr int W  = 1920, H = 1080;
constexpr int HW = W * H;
constexpr int Sh = 20, Wt = 160, R = 24;
constexpr int TX = W / Wt, TY = H / Sh;     // 12, 54
constexpr int SW = Sh * Wt;                 // 3200 px per tile
constexpr float LEAK_THR = (float)(R - 1);  // 23.0f

__global__ __launch_bounds__(512, 8) void dfp_tile(
    const float* __restrict__ flow, const float* __restrict__ depth,
    float* __restrict__ leak,      // [B*HW] float4 cells, zeroed
    float* __restrict__ cnt_out,   // raw tile cnt, stride cnt_stride
    int cnt_stride,
    float* __restrict__ out, int B)
{
    __shared__ __align__(16) float acc[3 * SW];   // cnt, sx, sy (38.4 KB)
    const int tid  = threadIdx.x;
    const int lane = tid & 63;
    const int wid  = tid >> 6;

    // XCD-aware swizzle (grid % 8 == 0 -> bijective simple form)
    int nwg  = gridDim.x;
    int orig = blockIdx.x;
    int blk  = ((nwg & 7) == 0) ? (orig & 7) * (nwg >> 3) + (orig >> 3) : orig;

    int b  = blk / (TX * TY);
    int t  = blk - b * (TX * TY);
    int ty = t / TX;
    int tx = t - ty * TX;
    const int Y0 = ty * Sh, X0 = tx * Wt;

    float4* accv = (float4*)acc;
    for (int i = tid; i < 3 * SW / 4; i += 512)
        accv[i] = make_float4(0.f, 0.f, 0.f, 0.f);
    __syncthreads();

    const float* fxp = flow + (size_t)b * 2 * HW;
    const float* fyp = fxp + HW;
    const float* dp  = depth + (size_t)b * HW;

    const int r0 = max(Y0 - R, 0), r1v = min(Y0 + Sh + R, H);
    const int c0 = max(X0 - R, 0), c1  = min(X0 + Wt + R, W);
    const int nch = (r1v - r0) * 2;   // 2 col-chunks (128 px each) per row

    // load one (row, chunk): 3 float2s per lane (6 independent dwords)
    auto ldchunk = [&](int idx, float2& f2x, float2& f2y, float2& d2,
                       int& row, int& colA, int& colL) {
        row  = r0 + (idx >> 1);
        colA = c0 + ((idx & 1) << 7) + (lane << 1);  // nominal col (px 0)
        colL = min(colA, c1 - 2);                    // clamped aligned load col
        size_t p = (size_t)row * W + colL;
        f2x = *(const float2*)(fxp + p);
        f2y = *(const float2*)(fyp + p);
        d2  = *(const float2*)(dp  + p);
    };

    auto proc = [&](int row, int colA, int colL, float fx, float fy, float dv, int j) {
        int col = colL + j;
        if ((colA + j) >= c1) return;                // clamped duplicate lane
        float x2 = (float)col + fx;
        float y2 = (float)row + fy;
        if (!(x2 >= 0.f && y2 >= 0.f && x2 <= (float)(W - 1) && y2 <= (float)(H - 1)))
            return;
        int ixL = min(max((int)floorf(x2), 0), W - 1);
        int iyT = min(max((int)floorf(y2), 0), H - 1);
        int ixR = min(ixL + 1, W - 1);
        int iyB = min(iyT + 1, H - 1);
        float vx = -fx * dv, vy = -fy * dv;

        if (fabsf(fx) <= LEAK_THR && fabsf(fy) <= LEAK_THR) {
            // corner offsets ⊆ [-24,+24] ⊆ halo -> add owned corners only
#define CORNER(iy, ix) do {                                              \
    if ((unsigned)((iy) - Y0) < (unsigned)Sh &&                          \
        (unsigned)((ix) - X0) < (unsigned)Wt) {                          \
        int o = ((iy) - Y0) * Wt + ((ix) - X0);                          \
        atomicAdd(&acc[o],          dv);                                 \
        atomicAdd(&acc[o + SW],     vx);                                 \
        atomicAdd(&acc[o + 2*SW],   vy);                                 \
    } } while (0)
            CORNER(iyT, ixL); CORNER(iyT, ixR);
            CORNER(iyB, ixL); CORNER(iyB, ixR);
#undef CORNER
        } else if ((unsigned)(row - Y0) < (unsigned)Sh &&
                   (unsigned)(col - X0) < (unsigned)Wt) {
            // rare big-flow pixel: handled once by its source-owning tile
            size_t base = (size_t)b * HW * 4;
#define GCORNER(iy, ix) do {                                             \
    size_t o = base + (size_t)((iy) * W + (ix)) * 4;                     \
    atomicAdd(leak + o + 0, dv);                                         \
    atomicAdd(leak + o + 1, vx);                                         \
    atomicAdd(leak + o + 2, vy);                                         \
    } while (0)
            GCORNER(iyT, ixL); GCORNER(iyT, ixR);
            GCORNER(iyB, ixL); GCORNER(iyB, ixR);
#undef GCORNER
        }
    };

    // 1-deep software-pipelined chunk loop (wave-uniform control)
    int idx = wid;
    float2 fxc, fyc, dc; int rowc, colAc, colLc;
    if (idx < nch) ldchunk(idx, fxc, fyc, dc, rowc, colAc, colLc);
    for (; idx < nch; idx += 8) {
        int nxt = idx + 8;
        float2 fxn, fyn, dn; int rown, colAn, colLn;
        if (nxt < nch) ldchunk(nxt, fxn, fyn, dn, rown, colAn, colLn);
        proc(rowc, colAc, colLc, fxc.x, fyc.x, dc.x, 0);
        proc(rowc, colAc, colLc, fxc.y, fyc.y, dc.y, 1);
        fxc = fxn; fyc = fyn; dc = dn;
        rowc = rown; colAc = colAn; colLc = colLn;
    }
    __syncthreads();

    // flush RAW sums: each output pixel owned by exactly one block
    float* outx = out + (size_t)b * 2 * HW;
    float* outy = outx + HW;
    for (int i = tid; i < SW; i += 512) {
        int ly = i / Wt;
        int lx = i - ly * Wt;
        int gp = (Y0 + ly) * W + (X0 + lx);
        outx[gp] = acc[i + SW];
        outy[gp] = acc[i + 2 * SW];
        cnt_out[(size_t)((size_t)b * HW + gp) * cnt_stride] = acc[i];
    }
}

// Kernel 2: combine tile sums + leak, normalize (stream-ordered -> race-free)
__global__ void dfp_finalize(const float4* __restrict__ leak,
                             const float* __restrict__ cnt_in,
                             int cnt_stride,
                             float* __restrict__ out, int B)
{
    const long total = (long)B * HW;
    long idx = (long)blockIdx.x * blockDim.x + threadIdx.x;
    if (idx >= total) return;
    int b = (int)(idx / HW);
    int p = (int)(idx - (long)b * HW);

    float4 lk = leak[idx];
    float cnt = cnt_in[(size_t)idx * cnt_stride] + lk.x;
    float den = (cnt > 0.f) ? cnt : 1.f;

    size_t o = (size_t)b * 2 * HW + p;
    out[o]      = (out[o]      + lk.y) / den;
    out[o + HW] = (out[o + HW] + lk.z) / den;
}

// ---------------- fallback (round-1) path if ws is too small ----------------

__global__ void dfp_scatter(const float* __restrict__ flow,
                            const float* __restrict__ depth,
                            float* __restrict__ out,
                            float* __restrict__ count, int B)
{
    const long total = (long)B * HW;
    long idx = (long)blockIdx.x * blockDim.x + threadIdx.x;
    if (idx >= total) return;
    int b = (int)(idx / HW);
    int p = (int)(idx - (long)b * HW);
    int y = p / W;
    int x = p - y * W;
    const float* f = flow + (size_t)b * 2 * HW;
    float fx = f[p], fy = f[HW + p], d = depth[idx];
    float x2 = (float)x + fx, y2 = (float)y + fy;
    if (!(x2 >= 0.f && y2 >= 0.f && x2 <= (float)(W - 1) && y2 <= (float)(H - 1)))
        return;
    int ixL = min(max((int)floorf(x2), 0), W - 1);
    int iyT = min(max((int)floorf(y2), 0), H - 1);
    int ixR = min(ixL + 1, W - 1), iyB = min(iyT + 1, H - 1);
    float vx = -fx * d, vy = -fy * d;
    float* cnt_b  = count + (size_t)b * HW;
    float* outx_b = out + (size_t)b * 2 * HW;
    float* outy_b = outx_b + HW;
    int o00 = iyT * W + ixL, o01 = iyT * W + ixR;
    int o10 = iyB * W + ixL, o11 = iyB * W + ixR;
    atomicAdd(&cnt_b[o00], d);   atomicAdd(&cnt_b[o01], d);
    atomicAdd(&cnt_b[o10], d);   atomicAdd(&cnt_b[o11], d);
    atomicAdd(&outx_b[o00], vx); atomicAdd(&outx_b[o01], vx);
    atomicAdd(&outx_b[o10], vx); atomicAdd(&outx_b[o11], vx);
    atomicAdd(&outy_b[o00], vy); atomicAdd(&outy_b[o01], vy);
    atomicAdd(&outy_b[o10], vy); atomicAdd(&outy_b[o11], vy);
}

__global__ void dfp_normalize(float* __restrict__ out,
                              const float* __restrict__ count, int B)
{
    const long total = (long)B * HW;
    long idx = (long)blockIdx.x * blockDim.x + threadIdx.x;
    if (idx >= total) return;
    int b = (int)(idx / HW);
    int p = (int)(idx - (long)b * HW);
    float c = count[idx];
    float den = (c > 0.f) ? c : 1.f;
    size_t o = (size_t)b * 2 * HW + p;
    out[o]      = out[o] / den;
    out[o + HW] = out[o + HW] / den;
}

extern "C" void kernel_launch(void* const* d_in, const int* in_sizes, int n_in,
                              void* d_out, int out_size, void* d_ws, size_t ws_size,
                              hipStream_t stream) {
    const float* flow  = (const float*)d_in[0];
    const float* depth = (const float*)d_in[1];
    float* out = (float*)d_out;

    const int B = in_sizes[1] / HW;
    const long total = (long)B * HW;

    const size_t cell_bytes  = (size_t)total * 4 * sizeof(float);
    const size_t plane_bytes = (size_t)total * sizeof(float);

    const int fin_threads = 256;
    const int fin_blocks  = (int)((total + fin_threads - 1) / fin_threads);

    if (ws_size >= cell_bytes + plane_bytes) {
        float* leak = (float*)d_ws;
        float* cnt  = leak + (size_t)total * 4;
        hipMemsetAsync(d_ws, 0, cell_bytes, stream);
        dfp_tile<<<B * TX * TY, 512, 0, stream>>>(flow, depth, leak, cnt, 1, out, B);
        dfp_finalize<<<fin_blocks, fin_threads, 0, stream>>>((const float4*)leak, cnt, 1, out, B);
    } else if (ws_size >= cell_bytes) {
        float* leak = (float*)d_ws;
        hipMemsetAsync(d_ws, 0, cell_bytes, stream);
        dfp_tile<<<B * TX * TY, 512, 0, stream>>>(flow, depth, leak, leak + 3, 4, out, B);
        dfp_finalize<<<fin_blocks, fin_threads, 0, stream>>>((const float4*)leak, leak + 3, 4, out, B);
    } else {
        const int threads = 256;
        const int blocks = (int)((total + threads - 1) / threads);
        float* cnt = (float*)d_ws;
        hipMemsetAsync(d_out, 0, (size_t)total * 2 * sizeof(float), stream);
        hipMemsetAsync(d_ws, 0, plane_bytes, stream);
        dfp_scatter<<<blocks, threads, 0, stream>>>(flow, depth, out, cnt, B);
        dfp_normalize<<<blocks, threads, 0, stream>>>(out, cnt, B);
    }
}

// Round 7
// 597.205 us; speedup vs baseline: 3.4055x; 1.0133x over previous
//
#include <hip/hip_runtime.h>

// DepthFlowProjection (DAIN, fillhole=0) forward — LDS-privatized scatter.
// R7: R6 structure (20x160 tile, 4 blocks/CU, branchy corner adds, leak
// path, 2-kernel finalize) + float4 row loads (one col pass, ~8.5
// row-iters/wave) + 2-deep software pipeline with named register slots.
// R5 lesson: predication/dummy-slot atomics serialize the DS pipe — keep
// corner adds divergent (execz skips them in the far halo).

constexpr int W  = 1920, H = 1080;
constexpr int HW = W * H;
constexpr int Sh = 20, Wt = 160, R = 24;
constexpr int TX = W / Wt, TY = H / Sh;     // 12, 54
constexpr int SW = Sh * Wt;                 // 3200 px per tile
constexpr float LEAK_THR = (float)(R - 1);  // 23.0f

__global__ __launch_bounds__(512, 8) void dfp_tile(
    const float* __restrict__ flow, const float* __restrict__ depth,
    float* __restrict__ leak,      // [B*HW] float4 cells, zeroed
    float* __restrict__ cnt_out,   // raw tile cnt, stride cnt_stride
    int cnt_stride,
    float* __restrict__ out, int B)
{
    __shared__ __align__(16) float acc[3 * SW];   // cnt, sx, sy (38.4 KB)
    const int tid  = threadIdx.x;
    const int lane = tid & 63;
    const int wid  = tid >> 6;

    // XCD-aware swizzle (grid % 8 == 0 here -> simple bijective form)
    int nwg  = gridDim.x;
    int orig = blockIdx.x;
    int blk  = ((nwg & 7) == 0) ? (orig & 7) * (nwg >> 3) + (orig >> 3) : orig;

    int b  = blk / (TX * TY);
    int t  = blk - b * (TX * TY);
    int ty = t / TX;
    int tx = t - ty * TX;
    const int Y0 = ty * Sh, X0 = tx * Wt;

    float4* accv = (float4*)acc;
    for (int i = tid; i < 3 * SW / 4; i += 512)
        accv[i] = make_float4(0.f, 0.f, 0.f, 0.f);
    __syncthreads();

    const float* fxp = flow + (size_t)b * 2 * HW;
    const float* fyp = fxp + HW;
    const float* dp  = depth + (size_t)b * HW;

    const int r0 = max(Y0 - R, 0), r1 = min(Y0 + Sh + R, H);
    const int c0 = max(X0 - R, 0), c1 = min(X0 + Wt + R, W);
    // c1-c0 is always a multiple of 4 (X0 mult of 160, R=24, W=1920):
    // lanes [0, (c1-c0)/4) are fully valid, the rest are duplicates.
    const int nlv = (c1 - c0) >> 2;      // # valid lanes (<= 52)
    const int ce  = c0 + (lane << 2);    // nominal first col of this lane
    const int cl  = min(ce, c1 - 4);     // clamped aligned load col

    auto ldrow = [&](int r, float4& f4x, float4& f4y, float4& d4) {
        size_t p = (size_t)r * W + cl;
        f4x = *(const float4*)(fxp + p);
        f4y = *(const float4*)(fyp + p);
        d4  = *(const float4*)(dp  + p);
    };

    auto proc1 = [&](int row, int col, float fx, float fy, float dv) {
        float x2 = (float)col + fx;
        float y2 = (float)row + fy;
        if (!(x2 >= 0.f && y2 >= 0.f && x2 <= (float)(W - 1) && y2 <= (float)(H - 1)))
            return;
        int ixL = min(max((int)floorf(x2), 0), W - 1);
        int iyT = min(max((int)floorf(y2), 0), H - 1);
        int ixR = min(ixL + 1, W - 1);
        int iyB = min(iyT + 1, H - 1);
        float vx = -fx * dv, vy = -fy * dv;

        if (fabsf(fx) <= LEAK_THR && fabsf(fy) <= LEAK_THR) {
            // corner offsets ⊆ [-24,+24] ⊆ halo -> add owned corners only
#define CORNER(iy, ix) do {                                              \
    if ((unsigned)((iy) - Y0) < (unsigned)Sh &&                          \
        (unsigned)((ix) - X0) < (unsigned)Wt) {                          \
        int o = ((iy) - Y0) * Wt + ((ix) - X0);                          \
        atomicAdd(&acc[o],          dv);                                 \
        atomicAdd(&acc[o + SW],     vx);                                 \
        atomicAdd(&acc[o + 2*SW],   vy);                                 \
    } } while (0)
            CORNER(iyT, ixL); CORNER(iyT, ixR);
            CORNER(iyB, ixL); CORNER(iyB, ixR);
#undef CORNER
        } else if ((unsigned)(row - Y0) < (unsigned)Sh &&
                   (unsigned)(col - X0) < (unsigned)Wt) {
            // rare big-flow pixel: handled once by its source-owning tile
            size_t base = (size_t)b * HW * 4;
#define GCORNER(iy, ix) do {                                             \
    size_t o = base + (size_t)((iy) * W + (ix)) * 4;                     \
    atomicAdd(leak + o + 0, dv);                                         \
    atomicAdd(leak + o + 1, vx);                                         \
    atomicAdd(leak + o + 2, vy);                                         \
    } while (0)
            GCORNER(iyT, ixL); GCORNER(iyT, ixR);
            GCORNER(iyB, ixL); GCORNER(iyB, ixR);
#undef GCORNER
        }
    };

    auto proc4 = [&](int row, const float4& f4x, const float4& f4y, const float4& d4) {
        if (lane >= nlv) return;         // duplicate tail lanes: nothing to do
        proc1(row, cl + 0, f4x.x, f4y.x, d4.x);
        proc1(row, cl + 1, f4x.y, f4y.y, d4.y);
        proc1(row, cl + 2, f4x.z, f4y.z, d4.z);
        proc1(row, cl + 3, f4x.w, f4y.w, d4.w);
    };

    // 2-deep software-pipelined row loop; named slots A/B (no runtime
    // indexing -> stays in registers). Slot A: rows r0+wid+16k,
    // slot B: rows r0+wid+8+16k.
    int r = r0 + wid;
    float4 fxA, fyA, dA, fxB, fyB, dB;
    if (r     < r1) ldrow(r,     fxA, fyA, dA);
    if (r + 8 < r1) ldrow(r + 8, fxB, fyB, dB);
    while (r < r1) {
        if (r + 16 < r1) {
            float4 t1, t2, t3;
            ldrow(r + 16, t1, t2, t3);
            proc4(r, fxA, fyA, dA);
            fxA = t1; fyA = t2; dA = t3;
        } else {
            proc4(r, fxA, fyA, dA);
        }
        r += 8;
        if (r >= r1) break;
        if (r + 16 < r1) {
            float4 t1, t2, t3;
            ldrow(r + 16, t1, t2, t3);
            proc4(r, fxB, fyB, dB);
            fxB = t1; fyB = t2; dB = t3;
        } else {
            proc4(r, fxB, fyB, dB);
        }
        r += 8;
    }
    __syncthreads();

    // flush RAW sums: each output pixel owned by exactly one block
    float* outx = out + (size_t)b * 2 * HW;
    float* outy = outx + HW;
    for (int i = tid; i < SW; i += 512) {
        int ly = i / Wt;
        int lx = i - ly * Wt;
        int gp = (Y0 + ly) * W + (X0 + lx);
        outx[gp] = acc[i + SW];
        outy[gp] = acc[i + 2 * SW];
        cnt_out[(size_t)((size_t)b * HW + gp) * cnt_stride] = acc[i];
    }
}

// Kernel 2: combine tile sums + leak, normalize (stream-ordered -> race-free)
__global__ void dfp_finalize(const float4* __restrict__ leak,
                             const float* __restrict__ cnt_in,
                             int cnt_stride,
                             float* __restrict__ out, int B)
{
    const long total = (long)B * HW;
    long idx = (long)blockIdx.x * blockDim.x + threadIdx.x;
    if (idx >= total) return;
    int b = (int)(idx / HW);
    int p = (int)(idx - (long)b * HW);

    float4 lk = leak[idx];
    float cnt = cnt_in[(size_t)idx * cnt_stride] + lk.x;
    float den = (cnt > 0.f) ? cnt : 1.f;

    size_t o = (size_t)b * 2 * HW + p;
    out[o]      = (out[o]      + lk.y) / den;
    out[o + HW] = (out[o + HW] + lk.z) / den;
}

// ---------------- fallback (round-1) path if ws is too small ----------------

__global__ void dfp_scatter(const float* __restrict__ flow,
                            const float* __restrict__ depth,
                            float* __restrict__ out,
                            float* __restrict__ count, int B)
{
    const long total = (long)B * HW;
    long idx = (long)blockIdx.x * blockDim.x + threadIdx.x;
    if (idx >= total) return;
    int b = (int)(idx / HW);
    int p = (int)(idx - (long)b * HW);
    int y = p / W;
    int x = p - y * W;
    const float* f = flow + (size_t)b * 2 * HW;
    float fx = f[p], fy = f[HW + p], d = depth[idx];
    float x2 = (float)x + fx, y2 = (float)y + fy;
    if (!(x2 >= 0.f && y2 >= 0.f && x2 <= (float)(W - 1) && y2 <= (float)(H - 1)))
        return;
    int ixL = min(max((int)floorf(x2), 0), W - 1);
    int iyT = min(max((int)floorf(y2), 0), H - 1);
    int ixR = min(ixL + 1, W - 1), iyB = min(iyT + 1, H - 1);
    float vx = -fx * d, vy = -fy * d;
    float* cnt_b  = count + (size_t)b * HW;
    float* outx_b = out + (size_t)b * 2 * HW;
    float* outy_b = outx_b + HW;
    int o00 = iyT * W + ixL, o01 = iyT * W + ixR;
    int o10 = iyB * W + ixL, o11 = iyB * W + ixR;
    atomicAdd(&cnt_b[o00], d);   atomicAdd(&cnt_b[o01], d);
    atomicAdd(&cnt_b[o10], d);   atomicAdd(&cnt_b[o11], d);
    atomicAdd(&outx_b[o00], vx); atomicAdd(&outx_b[o01], vx);
    atomicAdd(&outx_b[o10], vx); atomicAdd(&outx_b[o11], vx);
    atomicAdd(&outy_b[o00], vy); atomicAdd(&outy_b[o01], vy);
    atomicAdd(&outy_b[o10], vy); atomicAdd(&outy_b[o11], vy);
}

__global__ void dfp_normalize(float* __restrict__ out,
                              const float* __restrict__ count, int B)
{
    const long total = (long)B * HW;
    long idx = (long)blockIdx.x * blockDim.x + threadIdx.x;
    if (idx >= total) return;
    int b = (int)(idx / HW);
    int p = (int)(idx - (long)b * HW);
    float c = count[idx];
    float den = (c > 0.f) ? c : 1.f;
    size_t o = (size_t)b * 2 * HW + p;
    out[o]      = out[o] / den;
    out[o + HW] = out[o + HW] / den;
}

extern "C" void kernel_launch(void* const* d_in, const int* in_sizes, int n_in,
                              void* d_out, int out_size, void* d_ws, size_t ws_size,
                              hipStream_t stream) {
    const float* flow  = (const float*)d_in[0];
    const float* depth = (const float*)d_in[1];
    float* out = (float*)d_out;

    const int B = in_sizes[1] / HW;
    const long total = (long)B * HW;

    const size_t cell_bytes  = (size_t)total * 4 * sizeof(float);
    const size_t plane_bytes = (size_t)total * sizeof(float);

    const int fin_threads = 256;
    const int fin_blocks  = (int)((total + fin_threads - 1) / fin_threads);

    if (ws_size >= cell_bytes + plane_bytes) {
        float* leak = (float*)d_ws;
        float* cnt  = leak + (size_t)total * 4;
        hipMemsetAsync(d_ws, 0, cell_bytes, stream);
        dfp_tile<<<B * TX * TY, 512, 0, stream>>>(flow, depth, leak, cnt, 1, out, B);
        dfp_finalize<<<fin_blocks, fin_threads, 0, stream>>>((const float4*)leak, cnt, 1, out, B);
    } else if (ws_size >= cell_bytes) {
        float* leak = (float*)d_ws;
        hipMemsetAsync(d_ws, 0, cell_bytes, stream);
        dfp_tile<<<B * TX * TY, 512, 0, stream>>>(flow, depth, leak, leak + 3, 4, out, B);
        dfp_finalize<<<fin_blocks, fin_threads, 0, stream>>>((const float4*)leak, leak + 3, 4, out, B);
    } else {
        const int threads = 256;
        const int blocks = (int)((total + threads - 1) / threads);
        float* cnt = (float*)d_ws;
        hipMemsetAsync(d_out, 0, (size_t)total * 2 * sizeof(float), stream);
        hipMemsetAsync(d_ws, 0, plane_bytes, stream);
        dfp_scatter<<<blocks, threads, 0, stream>>>(flow, depth, out, cnt, B);
        dfp_normalize<<<blocks, threads, 0, stream>>>(out, cnt, B);
    }
}